// Round 14
// baseline (105.552 us; speedup 1.0000x reference)
//
#include <hip/hip_runtime.h>
#include <stdint.h>

#define AS1 __attribute__((address_space(1)))
#define AS3 __attribute__((address_space(3)))

typedef __attribute__((ext_vector_type(8))) short short8;
typedef __attribute__((ext_vector_type(4))) float f32x4;

#define CAP 64     // bucket capacity per node (deg = Poisson(16)+1; P(X>63) ~ 1e-16)
#define NGEMM 512  // 128 bm-tiles x 4 heads
#define NSCAT 128  // scatter blocks fused into the gemm dispatch
#define NW2T 256   // w2t blocks in dispatch 1
#define NCVT 2048  // convert blocks in dispatch 1

// ---------- bf16 helpers (RNE) ----------
__device__ __forceinline__ short f2bf(float f) {
  union { float f; unsigned u; } v; v.f = f;
  unsigned r = v.u + 0x7fffu + ((v.u >> 16) & 1u);
  return (short)(r >> 16);
}
__device__ __forceinline__ float bf_lo(unsigned w) { union { unsigned u; float f; } v; v.u = w << 16;          return v.f; }
__device__ __forceinline__ float bf_hi(unsigned w) { union { unsigned u; float f; } v; v.u = w & 0xffff0000u;  return v.f; }

// ---------- K1: fused {w2t (blocks 0..255)} || {text->bf16 convert (blocks 256..2303)} ----------
__global__ __launch_bounds__(256) void k_w2t_cvt(const float* __restrict__ W,
                                                 const float* __restrict__ F,
                                                 const float* __restrict__ text,
                                                 short* __restrict__ W2t,
                                                 short* __restrict__ textb,
                                                 int* __restrict__ cnt) {
  const int tid = threadIdx.x;
  const int b   = blockIdx.x;

  if (b >= NW2T) {                                 // ---- convert part ----
    const size_t base = (size_t)(b - NW2T) * 4096 + tid * 16;
    const float4* p = (const float4*)(text + base);
    float4 a0 = p[0], a1 = p[1], a2 = p[2], a3 = p[3];
    short8 o0, o1;
    o0[0] = f2bf(a0.x); o0[1] = f2bf(a0.y); o0[2] = f2bf(a0.z); o0[3] = f2bf(a0.w);
    o0[4] = f2bf(a1.x); o0[5] = f2bf(a1.y); o0[6] = f2bf(a1.z); o0[7] = f2bf(a1.w);
    o1[0] = f2bf(a2.x); o1[1] = f2bf(a2.y); o1[2] = f2bf(a2.z); o1[3] = f2bf(a2.w);
    o1[4] = f2bf(a3.x); o1[5] = f2bf(a3.y); o1[6] = f2bf(a3.z); o1[7] = f2bf(a3.w);
    *(short8*)(textb + base) = o0;
    *(short8*)(textb + base + 8) = o1;
    return;
  }

  // ---- w2t part ----
  if (tid < 64) cnt[b * 64 + tid] = 0;             // 256 blocks x 64 = N

  __shared__ float sW[64][36];  // [e][d]
  __shared__ float sF[64][36];  // [e][j]
  const int bx = b & 15, by = b >> 4;
  const int d0 = bx * 32, j0 = by * 32;
  const int dx = tid & 15, jy = tid >> 4;
  float a00 = 0.f, a01 = 0.f, a10 = 0.f, a11 = 0.f;
  const int wr = tid >> 3, wc = (tid & 7) * 8;
  const int fr = tid >> 2, fc = (tid & 3) * 8;
  for (int e0 = 0; e0 < 512; e0 += 64) {
    float4 w0 = *(const float4*)&W[(size_t)(d0 + wr) * 512 + e0 + wc];
    float4 w1 = *(const float4*)&W[(size_t)(d0 + wr) * 512 + e0 + wc + 4];
    float4 f0 = *(const float4*)&F[(size_t)(e0 + fr) * 512 + j0 + fc];
    float4 f1 = *(const float4*)&F[(size_t)(e0 + fr) * 512 + j0 + fc + 4];
    sW[wc + 0][wr] = w0.x; sW[wc + 1][wr] = w0.y; sW[wc + 2][wr] = w0.z; sW[wc + 3][wr] = w0.w;
    sW[wc + 4][wr] = w1.x; sW[wc + 5][wr] = w1.y; sW[wc + 6][wr] = w1.z; sW[wc + 7][wr] = w1.w;
    *(float4*)&sF[fr][fc] = f0;
    *(float4*)&sF[fr][fc + 4] = f1;
    __syncthreads();
#pragma unroll
    for (int e = 0; e < 64; ++e) {
      float2 w2 = *(const float2*)&sW[e][dx * 2];
      float2 f2 = *(const float2*)&sF[e][jy * 2];
      a00 += w2.x * f2.x; a01 += w2.x * f2.y;
      a10 += w2.y * f2.x; a11 += w2.y * f2.y;
    }
    __syncthreads();
  }
  short* o0 = W2t + (size_t)(j0 + jy * 2) * 512 + d0 + dx * 2;
  o0[0] = f2bf(a00); o0[1] = f2bf(a10);
  o0[512] = f2bf(a01); o0[513] = f2bf(a11);
}

// ---------- K2: fused {gemm 128x128x64 2-phase dbuf (blocks 0..511)} || {scatter (512..639)} ----------
// Both operands bf16 via global_load_lds (linear dest + inverse-XOR-swizzled src, rule 21).
// STAGE(next) issued BEFORE compute(cur); one __syncthreads per kt. XCD-local A-panels.
// C written 8-way-sliced: hs[2*hh+wn][node][64].
__global__ __launch_bounds__(256) void k_gemm_scatter(const short* __restrict__ A,
                                                      const short* __restrict__ Bt,
                                                      short* __restrict__ Cs,
                                                      float* __restrict__ el,
                                                      float* __restrict__ er,
                                                      const float* __restrict__ attn_l,
                                                      const float* __restrict__ attn_r,
                                                      const int* __restrict__ src,
                                                      const int* __restrict__ dst,
                                                      int* __restrict__ cnt,
                                                      int* __restrict__ bucket,
                                                      int E, int N) {
  const int tid = threadIdx.x;
  if (blockIdx.x >= NGEMM) {                       // ---- scatter part ----
    for (int e = (blockIdx.x - NGEMM) * 256 + tid; e < E; e += NSCAT * 256) {
      int d = dst[e];
      int p = atomicAdd(&cnt[d], 1);
      if (p < CAP) bucket[(size_t)d * CAP + p] = src[e];
    }
    return;
  }

  // ---- gemm part ----
  __shared__ __align__(16) short sA[2][128 * 64]; // 32 KB
  __shared__ __align__(16) short sB[2][128 * 64]; // 32 KB
  __shared__ float sEl[128][2];
  __shared__ float sEr[128][2];
  const int bx   = blockIdx.x;
  const int xcd  = bx & 7, kk = bx >> 3;
  const int bm0  = (xcd * 16 + (kk & 15)) * 128;  // same A-panel -> same XCD L2
  const int hh   = kk >> 4;                       // head == bn-block
  const int bn0  = hh * 128;
  const int lane = tid & 63;
  const int wid  = tid >> 6;
  const int wm   = wid >> 1;
  const int wn   = wid & 1;
  const int cc   = lane & 15;

  f32x4 acc[4][4] = {};

  const int srow  = tid >> 3;
  const int sslot = (tid & 7) ^ (srow & 7);
  const int lslot = tid & 7;

  // prologue: stage kt=0 into buf 0
#pragma unroll
  for (int r = 0; r < 4; ++r) {
    int row = r * 32 + srow;
    __builtin_amdgcn_global_load_lds((const AS1 void*)(A + (size_t)(bm0 + row) * 512 + sslot * 8),
                                     (AS3 void*)(sA[0] + row * 64 + lslot * 8), 16, 0, 0);
    __builtin_amdgcn_global_load_lds((const AS1 void*)(Bt + (size_t)(bn0 + row) * 512 + sslot * 8),
                                     (AS3 void*)(sB[0] + row * 64 + lslot * 8), 16, 0, 0);
  }
  __syncthreads();

  for (int kt = 0; kt < 8; ++kt) {
    const int cur = kt & 1;
    if (kt < 7) {                                  // stage kt+1 into the other buffer
      const int kbase = (kt + 1) * 64;
#pragma unroll
      for (int r = 0; r < 4; ++r) {
        int row = r * 32 + srow;
        __builtin_amdgcn_global_load_lds((const AS1 void*)(A + (size_t)(bm0 + row) * 512 + kbase + sslot * 8),
                                         (AS3 void*)(sA[cur ^ 1] + row * 64 + lslot * 8), 16, 0, 0);
        __builtin_amdgcn_global_load_lds((const AS1 void*)(Bt + (size_t)(bn0 + row) * 512 + kbase + sslot * 8),
                                         (AS3 void*)(sB[cur ^ 1] + row * 64 + lslot * 8), 16, 0, 0);
      }
    }
#pragma unroll
    for (int ks = 0; ks < 2; ++ks) {
      short8 af[4], bfr[4];
#pragma unroll
      for (int i = 0; i < 4; ++i) {
        int row  = wm * 64 + i * 16 + cc;
        int slot = (ks * 4 + (lane >> 4)) ^ (row & 7);
        af[i] = *(const short8*)(sA[cur] + row * 64 + slot * 8);
      }
#pragma unroll
      for (int j = 0; j < 4; ++j) {
        int row  = wn * 64 + j * 16 + cc;
        int slot = (ks * 4 + (lane >> 4)) ^ (row & 7);
        bfr[j] = *(const short8*)(sB[cur] + row * 64 + slot * 8);
      }
#pragma unroll
      for (int i = 0; i < 4; ++i)
#pragma unroll
        for (int j = 0; j < 4; ++j)
          acc[i][j] = __builtin_amdgcn_mfma_f32_16x16x32_bf16(af[i], bfr[j], acc[i][j], 0, 0, 0);
    }
    __syncthreads();
  }

  // C write, 8-way sliced: slice = 2*hh + wn, col = j*16+cc. C/D layout [m89-verified].
  const int r4 = (lane >> 4) * 4;
  const int sl8 = 2 * hh + wn;
#pragma unroll
  for (int i = 0; i < 4; ++i)
#pragma unroll
    for (int j = 0; j < 4; ++j) {
      int cin = j * 16 + cc;                       // 0..63 within slice
#pragma unroll
      for (int rg = 0; rg < 4; ++rg) {
        int gr = bm0 + wm * 64 + i * 16 + r4 + rg;
        Cs[((size_t)sl8 * N + gr) * 64 + cin] = f2bf(acc[i][j][rg]);
      }
    }
  // el/er partials -> LDS (2 partials per row), combine, store
  float alv[4], arv[4];
#pragma unroll
  for (int j = 0; j < 4; ++j) {
    int cl = wn * 64 + j * 16 + cc;
    alv[j] = attn_l[hh * 128 + cl];
    arv[j] = attn_r[hh * 128 + cl];
  }
#pragma unroll
  for (int i = 0; i < 4; ++i)
#pragma unroll
    for (int rg = 0; rg < 4; ++rg) {
      float pl = 0.f, pr = 0.f;
#pragma unroll
      for (int j = 0; j < 4; ++j) {
        float v = acc[i][j][rg];
        pl += v * alv[j]; pr += v * arv[j];
      }
#pragma unroll
      for (int d = 1; d < 16; d <<= 1) {
        pl += __shfl_xor(pl, d);
        pr += __shfl_xor(pr, d);
      }
      if (cc == 0) {
        int row = wm * 64 + i * 16 + r4 + rg;
        sEl[row][wn] = pl;
        sEr[row][wn] = pr;
      }
    }
  __syncthreads();
  if (tid < 128) {
    int gr = bm0 + tid;
    el[gr * 4 + hh] = sEl[tid][0] + sEl[tid][1];
    er[gr * 4 + hh] = sEr[tid][0] + sEr[tid][1];
  }
}

// ---------- K3: 8-way sliced aggregation. slice = blockIdx&7 -> one 2.1MB slice per XCD ----------
// Wave = one (node, slice): 8 edge-groups x 8 lanes (16B/lane, 128B/row), 2-deep, chain-free.
__global__ __launch_bounds__(256) void k_aggregate(const int* __restrict__ cnt, const int* __restrict__ bucket,
                                                   const float* __restrict__ el, const float* __restrict__ er,
                                                   const short* __restrict__ hs, const float* __restrict__ bias,
                                                   float* __restrict__ out, int N) {
  const int b    = blockIdx.x;
  const int s    = b & 7;                              // slice (head = s>>1)
  const int nd   = (b >> 3) * 4 + (threadIdx.x >> 6);
  const int lane = threadIdx.x & 63;
  const int g    = lane >> 3;                          // edge-parallel group 0..7
  const int cl   = lane & 7;                           // 16B chunk within 64-col slice

  int n = cnt[nd]; n = (n < CAP) ? n : CAP;            // n >= 1 (self-loop)
  const int* bk = bucket + (size_t)nd * CAP;

  int l   = (lane < n) ? lane : (n - 1);
  int idx = bk[l];
  float ern = er[nd * 4 + (s >> 1)];
  float x = el[idx * 4 + (s >> 1)] + ern;
  x = (x > 0.f) ? x : 0.2f * x;
  float wgt = (lane < n) ? __expf(x) : 0.f;            // zero pad => tail shuffles self-mask
  float ssum = wgt;
#pragma unroll
  for (int d = 1; d < 64; d <<= 1) ssum += __shfl_xor(ssum, d);

  const short* hbase = hs + (size_t)s * N * 64;
  float acc[8];
#pragma unroll
  for (int j = 0; j < 8; ++j) acc[j] = 0.f;

  for (int base = 0; base < n; base += 16) {           // 2-deep: edges base+g, base+8+g (<64 always)
    int e0 = base + g, e1 = base + 8 + g;
    int s0 = __shfl(idx, e0), s1 = __shfl(idx, e1);
    float w0 = __shfl(wgt, e0), w1 = __shfl(wgt, e1);
    uint4 v0 = ((const uint4*)(hbase + (size_t)s0 * 64))[cl];
    uint4 v1 = ((const uint4*)(hbase + (size_t)s1 * 64))[cl];
    acc[0] += w0 * bf_lo(v0.x) + w1 * bf_lo(v1.x);
    acc[1] += w0 * bf_hi(v0.x) + w1 * bf_hi(v1.x);
    acc[2] += w0 * bf_lo(v0.y) + w1 * bf_lo(v1.y);
    acc[3] += w0 * bf_hi(v0.y) + w1 * bf_hi(v1.y);
    acc[4] += w0 * bf_lo(v0.z) + w1 * bf_lo(v1.z);
    acc[5] += w0 * bf_hi(v0.z) + w1 * bf_hi(v1.z);
    acc[6] += w0 * bf_lo(v0.w) + w1 * bf_lo(v1.w);
    acc[7] += w0 * bf_hi(v0.w) + w1 * bf_hi(v1.w);
  }

  // combine the 8 edge-groups (same cl across groups: lanes differ in bits 3..5)
#pragma unroll
  for (int d = 8; d < 64; d <<= 1) {
#pragma unroll
    for (int j = 0; j < 8; ++j) acc[j] += __shfl_xor(acc[j], d);
  }

  if (g == 0) {
    float inv = 1.f / ssum;
    int c0 = s * 64 + cl * 8;
    float4 b0 = *(const float4*)(bias + c0);
    float4 b1 = *(const float4*)(bias + c0 + 4);
    float4 o0, o1;
    o0.x = acc[0] * inv + b0.x; o0.y = acc[1] * inv + b0.y;
    o0.z = acc[2] * inv + b0.z; o0.w = acc[3] * inv + b0.w;
    o1.x = acc[4] * inv + b1.x; o1.y = acc[5] * inv + b1.y;
    o1.z = acc[6] * inv + b1.z; o1.w = acc[7] * inv + b1.w;
    float* op = out + (size_t)nd * 512 + c0;
    *(float4*)op = o0;
    *(float4*)(op + 4) = o1;
  }
}

// ---------- launch ----------
extern "C" void kernel_launch(void* const* d_in, const int* in_sizes, int n_in,
                              void* d_out, int out_size, void* d_ws, size_t ws_size,
                              hipStream_t stream) {
  const float* text   = (const float*)d_in[0];
  const float* weight = (const float*)d_in[1];
  const float* fcw    = (const float*)d_in[2];
  const float* attn_l = (const float*)d_in[3];
  const float* attn_r = (const float*)d_in[4];
  const float* bias   = (const float*)d_in[5];
  const int*   src    = (const int*)d_in[6];
  const int*   dst    = (const int*)d_in[7];
  const int E = in_sizes[6];
  const int N = in_sizes[0] / 512;   // 16384

  char* ws = (char*)d_ws;
  size_t o = 0;
  auto carve = [&](size_t bytes) { void* p = ws + o; o = (o + bytes + 255) & ~(size_t)255; return p; };
  short* w2t    = (short*)carve((size_t)512 * 512 * 2);
  short* textb  = (short*)carve((size_t)N * 512 * 2);   // bf16 text
  short* hs     = (short*)carve((size_t)N * 512 * 2);   // 8-way sliced [8][N][64]
  float* el     = (float*)carve((size_t)N * 4 * 4);
  float* er     = (float*)carve((size_t)N * 4 * 4);
  int*   cnt    = (int*)carve((size_t)N * 4);
  int*   bucket = (int*)carve((size_t)N * CAP * 4);

  k_w2t_cvt<<<NW2T + NCVT, 256, 0, stream>>>(weight, fcw, text, w2t, textb, cnt);
  k_gemm_scatter<<<NGEMM + NSCAT, 256, 0, stream>>>(textb, w2t, hs, el, er, attn_l, attn_r,
                                                    src, dst, cnt, bucket, E, N);
  k_aggregate<<<N * 8 / 4, 256, 0, stream>>>(cnt, bucket, el, er, hs, bias, (float*)d_out, N);
}

// Round 15
// 83.772 us; speedup vs baseline: 1.2600x; 1.2600x over previous
//
#include <hip/hip_runtime.h>
#include <stdint.h>

#define AS1 __attribute__((address_space(1)))
#define AS3 __attribute__((address_space(3)))

typedef __attribute__((ext_vector_type(8))) short short8;
typedef __attribute__((ext_vector_type(4))) float f32x4;

#define CAP 64     // bucket capacity per node (deg = Poisson(16)+1; P(X>63) ~ 1e-16)
#define NGEMM 512  // 128 bm-tiles x 4 heads
#define NSCAT 128  // scatter blocks fused into the gemm dispatch
#define NW2T 256   // w2t blocks in dispatch 1
#define NCVT 2048  // convert blocks in dispatch 1

// ---------- bf16 helpers (RNE) ----------
__device__ __forceinline__ short f2bf(float f) {
  union { float f; unsigned u; } v; v.f = f;
  unsigned r = v.u + 0x7fffu + ((v.u >> 16) & 1u);
  return (short)(r >> 16);
}
__device__ __forceinline__ float bf_lo(unsigned w) { union { unsigned u; float f; } v; v.u = w << 16;          return v.f; }
__device__ __forceinline__ float bf_hi(unsigned w) { union { unsigned u; float f; } v; v.u = w & 0xffff0000u;  return v.f; }

// ---------- K1: fused {w2t (blocks 0..255)} || {text->bf16 convert (blocks 256..2303)} ----------
__global__ __launch_bounds__(256) void k_w2t_cvt(const float* __restrict__ W,
                                                 const float* __restrict__ F,
                                                 const float* __restrict__ text,
                                                 short* __restrict__ W2t,
                                                 short* __restrict__ textb,
                                                 int* __restrict__ cnt) {
  const int tid = threadIdx.x;
  const int b   = blockIdx.x;

  if (b >= NW2T) {                                 // ---- convert part ----
    const size_t base = (size_t)(b - NW2T) * 4096 + tid * 16;
    const float4* p = (const float4*)(text + base);
    float4 a0 = p[0], a1 = p[1], a2 = p[2], a3 = p[3];
    short8 o0, o1;
    o0[0] = f2bf(a0.x); o0[1] = f2bf(a0.y); o0[2] = f2bf(a0.z); o0[3] = f2bf(a0.w);
    o0[4] = f2bf(a1.x); o0[5] = f2bf(a1.y); o0[6] = f2bf(a1.z); o0[7] = f2bf(a1.w);
    o1[0] = f2bf(a2.x); o1[1] = f2bf(a2.y); o1[2] = f2bf(a2.z); o1[3] = f2bf(a2.w);
    o1[4] = f2bf(a3.x); o1[5] = f2bf(a3.y); o1[6] = f2bf(a3.z); o1[7] = f2bf(a3.w);
    *(short8*)(textb + base) = o0;
    *(short8*)(textb + base + 8) = o1;
    return;
  }

  // ---- w2t part ----
  if (tid < 64) cnt[b * 64 + tid] = 0;             // 256 blocks x 64 = N

  __shared__ float sW[64][36];  // [e][d]
  __shared__ float sF[64][36];  // [e][j]
  const int bx = b & 15, by = b >> 4;
  const int d0 = bx * 32, j0 = by * 32;
  const int dx = tid & 15, jy = tid >> 4;
  float a00 = 0.f, a01 = 0.f, a10 = 0.f, a11 = 0.f;
  const int wr = tid >> 3, wc = (tid & 7) * 8;
  const int fr = tid >> 2, fc = (tid & 3) * 8;
  for (int e0 = 0; e0 < 512; e0 += 64) {
    float4 w0 = *(const float4*)&W[(size_t)(d0 + wr) * 512 + e0 + wc];
    float4 w1 = *(const float4*)&W[(size_t)(d0 + wr) * 512 + e0 + wc + 4];
    float4 f0 = *(const float4*)&F[(size_t)(e0 + fr) * 512 + j0 + fc];
    float4 f1 = *(const float4*)&F[(size_t)(e0 + fr) * 512 + j0 + fc + 4];
    sW[wc + 0][wr] = w0.x; sW[wc + 1][wr] = w0.y; sW[wc + 2][wr] = w0.z; sW[wc + 3][wr] = w0.w;
    sW[wc + 4][wr] = w1.x; sW[wc + 5][wr] = w1.y; sW[wc + 6][wr] = w1.z; sW[wc + 7][wr] = w1.w;
    *(float4*)&sF[fr][fc] = f0;
    *(float4*)&sF[fr][fc + 4] = f1;
    __syncthreads();
#pragma unroll
    for (int e = 0; e < 64; ++e) {
      float2 w2 = *(const float2*)&sW[e][dx * 2];
      float2 f2 = *(const float2*)&sF[e][jy * 2];
      a00 += w2.x * f2.x; a01 += w2.x * f2.y;
      a10 += w2.y * f2.x; a11 += w2.y * f2.y;
    }
    __syncthreads();
  }
  short* o0 = W2t + (size_t)(j0 + jy * 2) * 512 + d0 + dx * 2;
  o0[0] = f2bf(a00); o0[1] = f2bf(a10);
  o0[512] = f2bf(a01); o0[513] = f2bf(a11);
}

// ---------- K2: fused {gemm 128x128x64 2-phase dbuf (blocks 0..511)} || {scatter (512..639)} ----------
// Both operands bf16 via global_load_lds (linear dest + inverse-XOR-swizzled src, rule 21).
// STAGE(next) issued BEFORE compute(cur); one __syncthreads per kt. XCD-local A-panels.
__global__ __launch_bounds__(256) void k_gemm_scatter(const short* __restrict__ A,
                                                      const short* __restrict__ Bt,
                                                      short* __restrict__ Cs,
                                                      float* __restrict__ el,
                                                      float* __restrict__ er,
                                                      const float* __restrict__ attn_l,
                                                      const float* __restrict__ attn_r,
                                                      const int* __restrict__ src,
                                                      const int* __restrict__ dst,
                                                      int* __restrict__ cnt,
                                                      int* __restrict__ bucket,
                                                      int E, int N) {
  const int tid = threadIdx.x;
  if (blockIdx.x >= NGEMM) {                       // ---- scatter part ----
    for (int e = (blockIdx.x - NGEMM) * 256 + tid; e < E; e += NSCAT * 256) {
      int d = dst[e];
      int p = atomicAdd(&cnt[d], 1);
      if (p < CAP) bucket[(size_t)d * CAP + p] = src[e];
    }
    return;
  }

  // ---- gemm part ----
  __shared__ __align__(16) short sA[2][128 * 64]; // 32 KB
  __shared__ __align__(16) short sB[2][128 * 64]; // 32 KB
  __shared__ float sEl[128][2];
  __shared__ float sEr[128][2];
  const int bx   = blockIdx.x;
  const int xcd  = bx & 7, kk = bx >> 3;
  const int bm0  = (xcd * 16 + (kk & 15)) * 128;  // same A-panel -> same XCD L2
  const int hh   = kk >> 4;                       // head == bn-block
  const int bn0  = hh * 128;
  const int lane = tid & 63;
  const int wid  = tid >> 6;
  const int wm   = wid >> 1;
  const int wn   = wid & 1;
  const int cc   = lane & 15;

  f32x4 acc[4][4] = {};

  const int srow  = tid >> 3;
  const int sslot = (tid & 7) ^ (srow & 7);
  const int lslot = tid & 7;

  // prologue: stage kt=0 into buf 0
#pragma unroll
  for (int r = 0; r < 4; ++r) {
    int row = r * 32 + srow;
    __builtin_amdgcn_global_load_lds((const AS1 void*)(A + (size_t)(bm0 + row) * 512 + sslot * 8),
                                     (AS3 void*)(sA[0] + row * 64 + lslot * 8), 16, 0, 0);
    __builtin_amdgcn_global_load_lds((const AS1 void*)(Bt + (size_t)(bn0 + row) * 512 + sslot * 8),
                                     (AS3 void*)(sB[0] + row * 64 + lslot * 8), 16, 0, 0);
  }
  __syncthreads();

  for (int kt = 0; kt < 8; ++kt) {
    const int cur = kt & 1;
    if (kt < 7) {                                  // stage kt+1 into the other buffer
      const int kbase = (kt + 1) * 64;
#pragma unroll
      for (int r = 0; r < 4; ++r) {
        int row = r * 32 + srow;
        __builtin_amdgcn_global_load_lds((const AS1 void*)(A + (size_t)(bm0 + row) * 512 + kbase + sslot * 8),
                                         (AS3 void*)(sA[cur ^ 1] + row * 64 + lslot * 8), 16, 0, 0);
        __builtin_amdgcn_global_load_lds((const AS1 void*)(Bt + (size_t)(bn0 + row) * 512 + kbase + sslot * 8),
                                         (AS3 void*)(sB[cur ^ 1] + row * 64 + lslot * 8), 16, 0, 0);
      }
    }
#pragma unroll
    for (int ks = 0; ks < 2; ++ks) {
      short8 af[4], bfr[4];
#pragma unroll
      for (int i = 0; i < 4; ++i) {
        int row  = wm * 64 + i * 16 + cc;
        int slot = (ks * 4 + (lane >> 4)) ^ (row & 7);
        af[i] = *(const short8*)(sA[cur] + row * 64 + slot * 8);
      }
#pragma unroll
      for (int j = 0; j < 4; ++j) {
        int row  = wn * 64 + j * 16 + cc;
        int slot = (ks * 4 + (lane >> 4)) ^ (row & 7);
        bfr[j] = *(const short8*)(sB[cur] + row * 64 + slot * 8);
      }
#pragma unroll
      for (int i = 0; i < 4; ++i)
#pragma unroll
        for (int j = 0; j < 4; ++j)
          acc[i][j] = __builtin_amdgcn_mfma_f32_16x16x32_bf16(af[i], bfr[j], acc[i][j], 0, 0, 0);
    }
    __syncthreads();
  }

  // C write, head-sliced hs[hh][node][128]. C/D layout: col=lane&15, row=(lane>>4)*4+reg
  const int r4 = (lane >> 4) * 4;
#pragma unroll
  for (int i = 0; i < 4; ++i)
#pragma unroll
    for (int j = 0; j < 4; ++j) {
      int cin = wn * 64 + j * 16 + cc;
#pragma unroll
      for (int rg = 0; rg < 4; ++rg) {
        int gr = bm0 + wm * 64 + i * 16 + r4 + rg;
        Cs[((size_t)hh * N + gr) * 128 + cin] = f2bf(acc[i][j][rg]);
      }
    }
  // el/er partials -> LDS (2 partials per row), combine, store
  float alv[4], arv[4];
#pragma unroll
  for (int j = 0; j < 4; ++j) {
    int cl = wn * 64 + j * 16 + cc;
    alv[j] = attn_l[hh * 128 + cl];
    arv[j] = attn_r[hh * 128 + cl];
  }
#pragma unroll
  for (int i = 0; i < 4; ++i)
#pragma unroll
    for (int rg = 0; rg < 4; ++rg) {
      float pl = 0.f, pr = 0.f;
#pragma unroll
      for (int j = 0; j < 4; ++j) {
        float v = acc[i][j][rg];
        pl += v * alv[j]; pr += v * arv[j];
      }
#pragma unroll
      for (int d = 1; d < 16; d <<= 1) {
        pl += __shfl_xor(pl, d);
        pr += __shfl_xor(pr, d);
      }
      if (cc == 0) {
        int row = wm * 64 + i * 16 + r4 + rg;
        sEl[row][wn] = pl;
        sEr[row][wn] = pr;
      }
    }
  __syncthreads();
  if (tid < 128) {
    int gr = bm0 + tid;
    el[gr * 4 + hh] = sEl[tid][0] + sEl[tid][1];
    er[gr * 4 + hh] = sEr[tid][0] + sEr[tid][1];
  }
}

// ---------- K3: 4-slice aggregation; ssum folded into the gather loop (no early serial reduce) ----------
// Slice s in blockIdx bits 1-2 -> each XCD sees one 4.2MB slice. Wave = (node, slice).
// Loop: 4 edge-groups x 2-deep; sw accumulates the shuffled weights (all 16 lanes of a group
// hold the same sw), so the full softmax denominator emerges from the same 2-step combine as acc.
__global__ __launch_bounds__(256) void k_aggregate(const int* __restrict__ cnt, const int* __restrict__ bucket,
                                                   const float* __restrict__ el, const float* __restrict__ er,
                                                   const short* __restrict__ hs, const float* __restrict__ bias,
                                                   float* __restrict__ out, int N) {
  const int b    = blockIdx.x;
  const int s    = (b >> 1) & 3;                       // head/slice
  const int nt   = (b >> 3) * 2 + (b & 1);             // node tile
  const int nd   = nt * 4 + (threadIdx.x >> 6);
  const int lane = threadIdx.x & 63;
  const int g    = lane >> 4;                          // edge-parallel group 0..3
  const int cl   = lane & 15;                          // 16B chunk within 128-col slice

  int n = cnt[nd]; n = (n < CAP) ? n : CAP;            // n >= 1 (self-loop)
  const int* bk = bucket + (size_t)nd * CAP;

  int l   = (lane < n) ? lane : (n - 1);
  int idx = bk[l];
  float ern = er[nd * 4 + s];
  float x = el[idx * 4 + s] + ern;
  x = (x > 0.f) ? x : 0.2f * x;
  float wgt = (lane < n) ? __expf(x) : 0.f;            // zero pad => tail shuffles self-mask

  const short* hbase = hs + (size_t)s * N * 128;
  float acc[8];
#pragma unroll
  for (int j = 0; j < 8; ++j) acc[j] = 0.f;
  float sw = 0.f;

  for (int base = 0; base < n; base += 8) {            // 2-deep: edges base+g, base+4+g
    int e0 = base + g, e1 = base + 4 + g;
    int s0 = __shfl(idx, e0), s1 = __shfl(idx, e1);
    float w0 = __shfl(wgt, e0), w1 = __shfl(wgt, e1);
    uint4 v0 = ((const uint4*)(hbase + (size_t)s0 * 128))[cl];
    uint4 v1 = ((const uint4*)(hbase + (size_t)s1 * 128))[cl];
    sw += w0 + w1;
    acc[0] += w0 * bf_lo(v0.x) + w1 * bf_lo(v1.x);
    acc[1] += w0 * bf_hi(v0.x) + w1 * bf_hi(v1.x);
    acc[2] += w0 * bf_lo(v0.y) + w1 * bf_lo(v1.y);
    acc[3] += w0 * bf_hi(v0.y) + w1 * bf_hi(v1.y);
    acc[4] += w0 * bf_lo(v0.z) + w1 * bf_lo(v1.z);
    acc[5] += w0 * bf_hi(v0.z) + w1 * bf_hi(v1.z);
    acc[6] += w0 * bf_lo(v0.w) + w1 * bf_lo(v1.w);
    acc[7] += w0 * bf_hi(v0.w) + w1 * bf_hi(v1.w);
  }

  // combine the 4 edge-groups; sw rides along (groups live in lane bits 4-5)
#pragma unroll
  for (int d = 16; d < 64; d <<= 1) {
    sw += __shfl_xor(sw, d);
#pragma unroll
    for (int j = 0; j < 8; ++j) acc[j] += __shfl_xor(acc[j], d);
  }

  if (g == 0) {
    float inv = 1.f / sw;                              // self-loop guarantees sw > 0
    int c0 = s * 128 + cl * 8;
    float4 b0 = *(const float4*)(bias + c0);
    float4 b1 = *(const float4*)(bias + c0 + 4);
    float4 o0, o1;
    o0.x = acc[0] * inv + b0.x; o0.y = acc[1] * inv + b0.y;
    o0.z = acc[2] * inv + b0.z; o0.w = acc[3] * inv + b0.w;
    o1.x = acc[4] * inv + b1.x; o1.y = acc[5] * inv + b1.y;
    o1.z = acc[6] * inv + b1.z; o1.w = acc[7] * inv + b1.w;
    float* op = out + (size_t)nd * 512 + c0;
    *(float4*)op = o0;
    *(float4*)(op + 4) = o1;
  }
}

// ---------- launch ----------
extern "C" void kernel_launch(void* const* d_in, const int* in_sizes, int n_in,
                              void* d_out, int out_size, void* d_ws, size_t ws_size,
                              hipStream_t stream) {
  const float* text   = (const float*)d_in[0];
  const float* weight = (const float*)d_in[1];
  const float* fcw    = (const float*)d_in[2];
  const float* attn_l = (const float*)d_in[3];
  const float* attn_r = (const float*)d_in[4];
  const float* bias   = (const float*)d_in[5];
  const int*   src    = (const int*)d_in[6];
  const int*   dst    = (const int*)d_in[7];
  const int E = in_sizes[6];
  const int N = in_sizes[0] / 512;   // 16384

  char* ws = (char*)d_ws;
  size_t o = 0;
  auto carve = [&](size_t bytes) { void* p = ws + o; o = (o + bytes + 255) & ~(size_t)255; return p; };
  short* w2t    = (short*)carve((size_t)512 * 512 * 2);
  short* textb  = (short*)carve((size_t)N * 512 * 2);   // bf16 text
  short* hs     = (short*)carve((size_t)N * 512 * 2);   // head-sliced [4][N][128]
  float* el     = (float*)carve((size_t)N * 4 * 4);
  float* er     = (float*)carve((size_t)N * 4 * 4);
  int*   cnt    = (int*)carve((size_t)N * 4);
  int*   bucket = (int*)carve((size_t)N * CAP * 4);

  k_w2t_cvt<<<NW2T + NCVT, 256, 0, stream>>>(weight, fcw, text, w2t, textb, cnt);
  k_gemm_scatter<<<NGEMM + NSCAT, 256, 0, stream>>>(textb, w2t, hs, el, er, attn_l, attn_r,
                                                    src, dst, cnt, bucket, E, N);
  k_aggregate<<<N * 4 / 4, 256, 0, stream>>>(cnt, bucket, el, er, hs, bias, (float*)d_out, N);
}

// Round 16
// 82.513 us; speedup vs baseline: 1.2792x; 1.0153x over previous
//
#include <hip/hip_runtime.h>
#include <stdint.h>

#define AS1 __attribute__((address_space(1)))
#define AS3 __attribute__((address_space(3)))

typedef __attribute__((ext_vector_type(8))) short short8;
typedef __attribute__((ext_vector_type(4))) float f32x4;

#define CAP 64     // bucket capacity per node (deg = Poisson(16)+1; P(X>63) ~ 1e-16)
#define NGEMM 512  // 128 bm-tiles x 4 heads
#define NSCAT 128  // scatter blocks fused into the gemm dispatch
#define NW2T 256   // w2t blocks in dispatch 1
#define NCVT 2048  // convert blocks in dispatch 1

// ---------- bf16 helpers (RNE) ----------
__device__ __forceinline__ short f2bf(float f) {
  union { float f; unsigned u; } v; v.f = f;
  unsigned r = v.u + 0x7fffu + ((v.u >> 16) & 1u);
  return (short)(r >> 16);
}
__device__ __forceinline__ float bf_lo(unsigned w) { union { unsigned u; float f; } v; v.u = w << 16;          return v.f; }
__device__ __forceinline__ float bf_hi(unsigned w) { union { unsigned u; float f; } v; v.u = w & 0xffff0000u;  return v.f; }

// ---------- K1: fused {w2t (blocks 0..255)} || {text->bf16 convert (blocks 256..2303)} ----------
__global__ __launch_bounds__(256) void k_w2t_cvt(const float* __restrict__ W,
                                                 const float* __restrict__ F,
                                                 const float* __restrict__ text,
                                                 short* __restrict__ W2t,
                                                 short* __restrict__ textb,
                                                 int* __restrict__ cnt) {
  const int tid = threadIdx.x;
  const int b   = blockIdx.x;

  if (b >= NW2T) {                                 // ---- convert part ----
    const size_t base = (size_t)(b - NW2T) * 4096 + tid * 16;
    const float4* p = (const float4*)(text + base);
    float4 a0 = p[0], a1 = p[1], a2 = p[2], a3 = p[3];
    short8 o0, o1;
    o0[0] = f2bf(a0.x); o0[1] = f2bf(a0.y); o0[2] = f2bf(a0.z); o0[3] = f2bf(a0.w);
    o0[4] = f2bf(a1.x); o0[5] = f2bf(a1.y); o0[6] = f2bf(a1.z); o0[7] = f2bf(a1.w);
    o1[0] = f2bf(a2.x); o1[1] = f2bf(a2.y); o1[2] = f2bf(a2.z); o1[3] = f2bf(a2.w);
    o1[4] = f2bf(a3.x); o1[5] = f2bf(a3.y); o1[6] = f2bf(a3.z); o1[7] = f2bf(a3.w);
    *(short8*)(textb + base) = o0;
    *(short8*)(textb + base + 8) = o1;
    return;
  }

  // ---- w2t part ----
  if (tid < 64) cnt[b * 64 + tid] = 0;             // 256 blocks x 64 = N

  __shared__ float sW[64][36];  // [e][d]
  __shared__ float sF[64][36];  // [e][j]
  const int bx = b & 15, by = b >> 4;
  const int d0 = bx * 32, j0 = by * 32;
  const int dx = tid & 15, jy = tid >> 4;
  float a00 = 0.f, a01 = 0.f, a10 = 0.f, a11 = 0.f;
  const int wr = tid >> 3, wc = (tid & 7) * 8;
  const int fr = tid >> 2, fc = (tid & 3) * 8;
  for (int e0 = 0; e0 < 512; e0 += 64) {
    float4 w0 = *(const float4*)&W[(size_t)(d0 + wr) * 512 + e0 + wc];
    float4 w1 = *(const float4*)&W[(size_t)(d0 + wr) * 512 + e0 + wc + 4];
    float4 f0 = *(const float4*)&F[(size_t)(e0 + fr) * 512 + j0 + fc];
    float4 f1 = *(const float4*)&F[(size_t)(e0 + fr) * 512 + j0 + fc + 4];
    sW[wc + 0][wr] = w0.x; sW[wc + 1][wr] = w0.y; sW[wc + 2][wr] = w0.z; sW[wc + 3][wr] = w0.w;
    sW[wc + 4][wr] = w1.x; sW[wc + 5][wr] = w1.y; sW[wc + 6][wr] = w1.z; sW[wc + 7][wr] = w1.w;
    *(float4*)&sF[fr][fc] = f0;
    *(float4*)&sF[fr][fc + 4] = f1;
    __syncthreads();
#pragma unroll
    for (int e = 0; e < 64; ++e) {
      float2 w2 = *(const float2*)&sW[e][dx * 2];
      float2 f2 = *(const float2*)&sF[e][jy * 2];
      a00 += w2.x * f2.x; a01 += w2.x * f2.y;
      a10 += w2.y * f2.x; a11 += w2.y * f2.y;
    }
    __syncthreads();
  }
  short* o0 = W2t + (size_t)(j0 + jy * 2) * 512 + d0 + dx * 2;
  o0[0] = f2bf(a00); o0[1] = f2bf(a10);
  o0[512] = f2bf(a01); o0[513] = f2bf(a11);
}

// ---------- K2: fused {gemm 128x128x64 2-phase dbuf (blocks 0..511)} || {scatter (512..639)} ----------
// Both operands bf16 via global_load_lds (linear dest + inverse-XOR-swizzled src, rule 21).
// STAGE(next) issued BEFORE compute(cur); one __syncthreads per kt. XCD-local A-panels.
__global__ __launch_bounds__(256) void k_gemm_scatter(const short* __restrict__ A,
                                                      const short* __restrict__ Bt,
                                                      short* __restrict__ Cs,
                                                      float* __restrict__ el,
                                                      float* __restrict__ er,
                                                      const float* __restrict__ attn_l,
                                                      const float* __restrict__ attn_r,
                                                      const int* __restrict__ src,
                                                      const int* __restrict__ dst,
                                                      int* __restrict__ cnt,
                                                      int* __restrict__ bucket,
                                                      int E, int N) {
  const int tid = threadIdx.x;
  if (blockIdx.x >= NGEMM) {                       // ---- scatter part ----
    for (int e = (blockIdx.x - NGEMM) * 256 + tid; e < E; e += NSCAT * 256) {
      int d = dst[e];
      int p = atomicAdd(&cnt[d], 1);
      if (p < CAP) bucket[(size_t)d * CAP + p] = src[e];
    }
    return;
  }

  // ---- gemm part ----
  __shared__ __align__(16) short sA[2][128 * 64]; // 32 KB
  __shared__ __align__(16) short sB[2][128 * 64]; // 32 KB
  __shared__ float sEl[128][2];
  __shared__ float sEr[128][2];
  const int bx   = blockIdx.x;
  const int xcd  = bx & 7, kk = bx >> 3;
  const int bm0  = (xcd * 16 + (kk & 15)) * 128;  // same A-panel -> same XCD L2
  const int hh   = kk >> 4;                       // head == bn-block
  const int bn0  = hh * 128;
  const int lane = tid & 63;
  const int wid  = tid >> 6;
  const int wm   = wid >> 1;
  const int wn   = wid & 1;
  const int cc   = lane & 15;

  f32x4 acc[4][4] = {};

  const int srow  = tid >> 3;
  const int sslot = (tid & 7) ^ (srow & 7);
  const int lslot = tid & 7;

  // prologue: stage kt=0 into buf 0
#pragma unroll
  for (int r = 0; r < 4; ++r) {
    int row = r * 32 + srow;
    __builtin_amdgcn_global_load_lds((const AS1 void*)(A + (size_t)(bm0 + row) * 512 + sslot * 8),
                                     (AS3 void*)(sA[0] + row * 64 + lslot * 8), 16, 0, 0);
    __builtin_amdgcn_global_load_lds((const AS1 void*)(Bt + (size_t)(bn0 + row) * 512 + sslot * 8),
                                     (AS3 void*)(sB[0] + row * 64 + lslot * 8), 16, 0, 0);
  }
  __syncthreads();

  for (int kt = 0; kt < 8; ++kt) {
    const int cur = kt & 1;
    if (kt < 7) {                                  // stage kt+1 into the other buffer
      const int kbase = (kt + 1) * 64;
#pragma unroll
      for (int r = 0; r < 4; ++r) {
        int row = r * 32 + srow;
        __builtin_amdgcn_global_load_lds((const AS1 void*)(A + (size_t)(bm0 + row) * 512 + kbase + sslot * 8),
                                         (AS3 void*)(sA[cur ^ 1] + row * 64 + lslot * 8), 16, 0, 0);
        __builtin_amdgcn_global_load_lds((const AS1 void*)(Bt + (size_t)(bn0 + row) * 512 + kbase + sslot * 8),
                                         (AS3 void*)(sB[cur ^ 1] + row * 64 + lslot * 8), 16, 0, 0);
      }
    }
#pragma unroll
    for (int ks = 0; ks < 2; ++ks) {
      short8 af[4], bfr[4];
#pragma unroll
      for (int i = 0; i < 4; ++i) {
        int row  = wm * 64 + i * 16 + cc;
        int slot = (ks * 4 + (lane >> 4)) ^ (row & 7);
        af[i] = *(const short8*)(sA[cur] + row * 64 + slot * 8);
      }
#pragma unroll
      for (int j = 0; j < 4; ++j) {
        int row  = wn * 64 + j * 16 + cc;
        int slot = (ks * 4 + (lane >> 4)) ^ (row & 7);
        bfr[j] = *(const short8*)(sB[cur] + row * 64 + slot * 8);
      }
#pragma unroll
      for (int i = 0; i < 4; ++i)
#pragma unroll
        for (int j = 0; j < 4; ++j)
          acc[i][j] = __builtin_amdgcn_mfma_f32_16x16x32_bf16(af[i], bfr[j], acc[i][j], 0, 0, 0);
    }
    __syncthreads();
  }

  // C write, head-sliced hs[hh][node][128]. C/D layout: col=lane&15, row=(lane>>4)*4+reg
  const int r4 = (lane >> 4) * 4;
#pragma unroll
  for (int i = 0; i < 4; ++i)
#pragma unroll
    for (int j = 0; j < 4; ++j) {
      int cin = wn * 64 + j * 16 + cc;
#pragma unroll
      for (int rg = 0; rg < 4; ++rg) {
        int gr = bm0 + wm * 64 + i * 16 + r4 + rg;
        Cs[((size_t)hh * N + gr) * 128 + cin] = f2bf(acc[i][j][rg]);
      }
    }
  // el/er partials -> LDS (2 partials per row), combine, store
  float alv[4], arv[4];
#pragma unroll
  for (int j = 0; j < 4; ++j) {
    int cl = wn * 64 + j * 16 + cc;
    alv[j] = attn_l[hh * 128 + cl];
    arv[j] = attn_r[hh * 128 + cl];
  }
#pragma unroll
  for (int i = 0; i < 4; ++i)
#pragma unroll
    for (int rg = 0; rg < 4; ++rg) {
      float pl = 0.f, pr = 0.f;
#pragma unroll
      for (int j = 0; j < 4; ++j) {
        float v = acc[i][j][rg];
        pl += v * alv[j]; pr += v * arv[j];
      }
#pragma unroll
      for (int d = 1; d < 16; d <<= 1) {
        pl += __shfl_xor(pl, d);
        pr += __shfl_xor(pr, d);
      }
      if (cc == 0) {
        int row = wm * 64 + i * 16 + r4 + rg;
        sEl[row][wn] = pl;
        sEr[row][wn] = pr;
      }
    }
  __syncthreads();
  if (tid < 128) {
    int gr = bm0 + tid;
    el[gr * 4 + hh] = sEl[tid][0] + sEl[tid][1];
    er[gr * 4 + hh] = sEr[tid][0] + sEr[tid][1];
  }
}

// ---------- K3: 4-slice aggregation; parallel prologue loads (cnt/bk/er issue together) ----------
// bk[lane] is loaded UNCONDITIONALLY (always within the CAP=64 allocation); idx is clamped to 0
// for lane>=n after the load returns (wgt=0 masks any contribution) -> the cnt->bk dependent
// chain disappears; only the el-gather remains serial. ssum folded into the gather loop.
__global__ __launch_bounds__(256) void k_aggregate(const int* __restrict__ cnt, const int* __restrict__ bucket,
                                                   const float* __restrict__ el, const float* __restrict__ er,
                                                   const short* __restrict__ hs, const float* __restrict__ bias,
                                                   float* __restrict__ out, int N) {
  const int b    = blockIdx.x;
  const int s    = (b >> 1) & 3;                       // head/slice
  const int nt   = (b >> 3) * 2 + (b & 1);             // node tile
  const int nd   = nt * 4 + (threadIdx.x >> 6);
  const int lane = threadIdx.x & 63;
  const int g    = lane >> 4;                          // edge-parallel group 0..3
  const int cl   = lane & 15;                          // 16B chunk within 128-col slice

  // parallel prologue: all three loads independent
  int n_raw   = cnt[nd];
  int idx_raw = bucket[(size_t)nd * CAP + lane];       // always in-allocation; poison if lane>=n
  float ern   = er[nd * 4 + s];

  int n = (n_raw < CAP) ? n_raw : CAP;                 // n >= 1 (self-loop)
  bool live = lane < n;
  int idx = live ? idx_raw : 0;                        // clamp AFTER load: valid gather address
  float x = el[idx * 4 + s] + ern;
  x = (x > 0.f) ? x : 0.2f * x;
  float wgt = live ? __expf(x) : 0.f;                  // zero pad => tail shuffles self-mask

  const short* hbase = hs + (size_t)s * N * 128;
  float acc[8];
#pragma unroll
  for (int j = 0; j < 8; ++j) acc[j] = 0.f;
  float sw = 0.f;

  for (int base = 0; base < n; base += 8) {            // 2-deep: edges base+g, base+4+g
    int e0 = base + g, e1 = base + 4 + g;
    int s0 = __shfl(idx, e0), s1 = __shfl(idx, e1);
    float w0 = __shfl(wgt, e0), w1 = __shfl(wgt, e1);
    uint4 v0 = ((const uint4*)(hbase + (size_t)s0 * 128))[cl];
    uint4 v1 = ((const uint4*)(hbase + (size_t)s1 * 128))[cl];
    sw += w0 + w1;
    acc[0] += w0 * bf_lo(v0.x) + w1 * bf_lo(v1.x);
    acc[1] += w0 * bf_hi(v0.x) + w1 * bf_hi(v1.x);
    acc[2] += w0 * bf_lo(v0.y) + w1 * bf_lo(v1.y);
    acc[3] += w0 * bf_hi(v0.y) + w1 * bf_hi(v1.y);
    acc[4] += w0 * bf_lo(v0.z) + w1 * bf_lo(v1.z);
    acc[5] += w0 * bf_hi(v0.z) + w1 * bf_hi(v1.z);
    acc[6] += w0 * bf_lo(v0.w) + w1 * bf_lo(v1.w);
    acc[7] += w0 * bf_hi(v0.w) + w1 * bf_hi(v1.w);
  }

  // combine the 4 edge-groups; sw rides along (groups live in lane bits 4-5)
#pragma unroll
  for (int d = 16; d < 64; d <<= 1) {
    sw += __shfl_xor(sw, d);
#pragma unroll
    for (int j = 0; j < 8; ++j) acc[j] += __shfl_xor(acc[j], d);
  }

  if (g == 0) {
    float inv = 1.f / sw;                              // self-loop guarantees sw > 0
    int c0 = s * 128 + cl * 8;
    float4 b0 = *(const float4*)(bias + c0);
    float4 b1 = *(const float4*)(bias + c0 + 4);
    float4 o0, o1;
    o0.x = acc[0] * inv + b0.x; o0.y = acc[1] * inv + b0.y;
    o0.z = acc[2] * inv + b0.z; o0.w = acc[3] * inv + b0.w;
    o1.x = acc[4] * inv + b1.x; o1.y = acc[5] * inv + b1.y;
    o1.z = acc[6] * inv + b1.z; o1.w = acc[7] * inv + b1.w;
    float* op = out + (size_t)nd * 512 + c0;
    *(float4*)op = o0;
    *(float4*)(op + 4) = o1;
  }
}

// ---------- launch ----------
extern "C" void kernel_launch(void* const* d_in, const int* in_sizes, int n_in,
                              void* d_out, int out_size, void* d_ws, size_t ws_size,
                              hipStream_t stream) {
  const float* text   = (const float*)d_in[0];
  const float* weight = (const float*)d_in[1];
  const float* fcw    = (const float*)d_in[2];
  const float* attn_l = (const float*)d_in[3];
  const float* attn_r = (const float*)d_in[4];
  const float* bias   = (const float*)d_in[5];
  const int*   src    = (const int*)d_in[6];
  const int*   dst    = (const int*)d_in[7];
  const int E = in_sizes[6];
  const int N = in_sizes[0] / 512;   // 16384

  char* ws = (char*)d_ws;
  size_t o = 0;
  auto carve = [&](size_t bytes) { void* p = ws + o; o = (o + bytes + 255) & ~(size_t)255; return p; };
  short* w2t    = (short*)carve((size_t)512 * 512 * 2);
  short* textb  = (short*)carve((size_t)N * 512 * 2);   // bf16 text
  short* hs     = (short*)carve((size_t)N * 512 * 2);   // head-sliced [4][N][128]
  float* el     = (float*)carve((size_t)N * 4 * 4);
  float* er     = (float*)carve((size_t)N * 4 * 4);
  int*   cnt    = (int*)carve((size_t)N * 4);
  int*   bucket = (int*)carve((size_t)N * CAP * 4);

  k_w2t_cvt<<<NW2T + NCVT, 256, 0, stream>>>(weight, fcw, text, w2t, textb, cnt);
  k_gemm_scatter<<<NGEMM + NSCAT, 256, 0, stream>>>(textb, w2t, hs, el, er, attn_l, attn_r,
                                                    src, dst, cnt, bucket, E, N);
  k_aggregate<<<N * 4 / 4, 256, 0, stream>>>(cnt, bucket, el, er, hs, bias, (float*)d_out, N);
}

// Round 17
// 81.902 us; speedup vs baseline: 1.2888x; 1.0075x over previous
//
#include <hip/hip_runtime.h>
#include <stdint.h>

#define AS1 __attribute__((address_space(1)))
#define AS3 __attribute__((address_space(3)))

typedef __attribute__((ext_vector_type(8))) short short8;
typedef __attribute__((ext_vector_type(4))) float f32x4;

#define CAP 64     // bucket capacity per node (deg = Poisson(16)+1; P(X>63) ~ 1e-16)
#define NGEMM 512  // 128 bm-tiles x 4 heads
#define NSCAT 128  // scatter blocks fused into the gemm dispatch
#define NW2T 256   // w2t blocks in dispatch 1
#define NCVT 2048  // convert blocks in dispatch 1

// ---------- bf16 helpers (RNE) ----------
__device__ __forceinline__ short f2bf(float f) {
  union { float f; unsigned u; } v; v.f = f;
  unsigned r = v.u + 0x7fffu + ((v.u >> 16) & 1u);
  return (short)(r >> 16);
}
__device__ __forceinline__ float bf_lo(unsigned w) { union { unsigned u; float f; } v; v.u = w << 16;          return v.f; }
__device__ __forceinline__ float bf_hi(unsigned w) { union { unsigned u; float f; } v; v.u = w & 0xffff0000u;  return v.f; }

// ---------- K1: fused {w2t (blocks 0..255)} || {text->bf16 convert (blocks 256..2303)} ----------
__global__ __launch_bounds__(256) void k_w2t_cvt(const float* __restrict__ W,
                                                 const float* __restrict__ F,
                                                 const float* __restrict__ text,
                                                 short* __restrict__ W2t,
                                                 short* __restrict__ textb,
                                                 int* __restrict__ cnt) {
  const int tid = threadIdx.x;
  const int b   = blockIdx.x;

  if (b >= NW2T) {                                 // ---- convert part ----
    const size_t base = (size_t)(b - NW2T) * 4096 + tid * 16;
    const float4* p = (const float4*)(text + base);
    float4 a0 = p[0], a1 = p[1], a2 = p[2], a3 = p[3];
    short8 o0, o1;
    o0[0] = f2bf(a0.x); o0[1] = f2bf(a0.y); o0[2] = f2bf(a0.z); o0[3] = f2bf(a0.w);
    o0[4] = f2bf(a1.x); o0[5] = f2bf(a1.y); o0[6] = f2bf(a1.z); o0[7] = f2bf(a1.w);
    o1[0] = f2bf(a2.x); o1[1] = f2bf(a2.y); o1[2] = f2bf(a2.z); o1[3] = f2bf(a2.w);
    o1[4] = f2bf(a3.x); o1[5] = f2bf(a3.y); o1[6] = f2bf(a3.z); o1[7] = f2bf(a3.w);
    *(short8*)(textb + base) = o0;
    *(short8*)(textb + base + 8) = o1;
    return;
  }

  // ---- w2t part ----
  if (tid < 64) cnt[b * 64 + tid] = 0;             // 256 blocks x 64 = N

  __shared__ float sW[64][36];  // [e][d]
  __shared__ float sF[64][36];  // [e][j]
  const int bx = b & 15, by = b >> 4;
  const int d0 = bx * 32, j0 = by * 32;
  const int dx = tid & 15, jy = tid >> 4;
  float a00 = 0.f, a01 = 0.f, a10 = 0.f, a11 = 0.f;
  const int wr = tid >> 3, wc = (tid & 7) * 8;
  const int fr = tid >> 2, fc = (tid & 3) * 8;
  for (int e0 = 0; e0 < 512; e0 += 64) {
    float4 w0 = *(const float4*)&W[(size_t)(d0 + wr) * 512 + e0 + wc];
    float4 w1 = *(const float4*)&W[(size_t)(d0 + wr) * 512 + e0 + wc + 4];
    float4 f0 = *(const float4*)&F[(size_t)(e0 + fr) * 512 + j0 + fc];
    float4 f1 = *(const float4*)&F[(size_t)(e0 + fr) * 512 + j0 + fc + 4];
    sW[wc + 0][wr] = w0.x; sW[wc + 1][wr] = w0.y; sW[wc + 2][wr] = w0.z; sW[wc + 3][wr] = w0.w;
    sW[wc + 4][wr] = w1.x; sW[wc + 5][wr] = w1.y; sW[wc + 6][wr] = w1.z; sW[wc + 7][wr] = w1.w;
    *(float4*)&sF[fr][fc] = f0;
    *(float4*)&sF[fr][fc + 4] = f1;
    __syncthreads();
#pragma unroll
    for (int e = 0; e < 64; ++e) {
      float2 w2 = *(const float2*)&sW[e][dx * 2];
      float2 f2 = *(const float2*)&sF[e][jy * 2];
      a00 += w2.x * f2.x; a01 += w2.x * f2.y;
      a10 += w2.y * f2.x; a11 += w2.y * f2.y;
    }
    __syncthreads();
  }
  short* o0 = W2t + (size_t)(j0 + jy * 2) * 512 + d0 + dx * 2;
  o0[0] = f2bf(a00); o0[1] = f2bf(a10);
  o0[512] = f2bf(a01); o0[513] = f2bf(a11);
}

// ---------- K2: fused {gemm 128x128x64 2-phase dbuf (blocks 0..511)} || {scatter (512..639)} ----------
// Both operands bf16 via global_load_lds (linear dest + inverse-XOR-swizzled src, rule 21).
// STAGE(next) issued BEFORE compute(cur); one __syncthreads per kt. XCD-local A-panels.
__global__ __launch_bounds__(256) void k_gemm_scatter(const short* __restrict__ A,
                                                      const short* __restrict__ Bt,
                                                      short* __restrict__ Cs,
                                                      float* __restrict__ el,
                                                      float* __restrict__ er,
                                                      const float* __restrict__ attn_l,
                                                      const float* __restrict__ attn_r,
                                                      const int* __restrict__ src,
                                                      const int* __restrict__ dst,
                                                      int* __restrict__ cnt,
                                                      int* __restrict__ bucket,
                                                      int E, int N) {
  const int tid = threadIdx.x;
  if (blockIdx.x >= NGEMM) {                       // ---- scatter part ----
    for (int e = (blockIdx.x - NGEMM) * 256 + tid; e < E; e += NSCAT * 256) {
      int d = dst[e];
      int p = atomicAdd(&cnt[d], 1);
      if (p < CAP) bucket[(size_t)d * CAP + p] = src[e];
    }
    return;
  }

  // ---- gemm part ----
  __shared__ __align__(16) short sA[2][128 * 64]; // 32 KB
  __shared__ __align__(16) short sB[2][128 * 64]; // 32 KB
  __shared__ float sEl[128][2];
  __shared__ float sEr[128][2];
  const int bx   = blockIdx.x;
  const int xcd  = bx & 7, kk = bx >> 3;
  const int bm0  = (xcd * 16 + (kk & 15)) * 128;  // same A-panel -> same XCD L2
  const int hh   = kk >> 4;                       // head == bn-block
  const int bn0  = hh * 128;
  const int lane = tid & 63;
  const int wid  = tid >> 6;
  const int wm   = wid >> 1;
  const int wn   = wid & 1;
  const int cc   = lane & 15;

  f32x4 acc[4][4] = {};

  const int srow  = tid >> 3;
  const int sslot = (tid & 7) ^ (srow & 7);
  const int lslot = tid & 7;

  // prologue: stage kt=0 into buf 0
#pragma unroll
  for (int r = 0; r < 4; ++r) {
    int row = r * 32 + srow;
    __builtin_amdgcn_global_load_lds((const AS1 void*)(A + (size_t)(bm0 + row) * 512 + sslot * 8),
                                     (AS3 void*)(sA[0] + row * 64 + lslot * 8), 16, 0, 0);
    __builtin_amdgcn_global_load_lds((const AS1 void*)(Bt + (size_t)(bn0 + row) * 512 + sslot * 8),
                                     (AS3 void*)(sB[0] + row * 64 + lslot * 8), 16, 0, 0);
  }
  __syncthreads();

  for (int kt = 0; kt < 8; ++kt) {
    const int cur = kt & 1;
    if (kt < 7) {                                  // stage kt+1 into the other buffer
      const int kbase = (kt + 1) * 64;
#pragma unroll
      for (int r = 0; r < 4; ++r) {
        int row = r * 32 + srow;
        __builtin_amdgcn_global_load_lds((const AS1 void*)(A + (size_t)(bm0 + row) * 512 + kbase + sslot * 8),
                                         (AS3 void*)(sA[cur ^ 1] + row * 64 + lslot * 8), 16, 0, 0);
        __builtin_amdgcn_global_load_lds((const AS1 void*)(Bt + (size_t)(bn0 + row) * 512 + kbase + sslot * 8),
                                         (AS3 void*)(sB[cur ^ 1] + row * 64 + lslot * 8), 16, 0, 0);
      }
    }
#pragma unroll
    for (int ks = 0; ks < 2; ++ks) {
      short8 af[4], bfr[4];
#pragma unroll
      for (int i = 0; i < 4; ++i) {
        int row  = wm * 64 + i * 16 + cc;
        int slot = (ks * 4 + (lane >> 4)) ^ (row & 7);
        af[i] = *(const short8*)(sA[cur] + row * 64 + slot * 8);
      }
#pragma unroll
      for (int j = 0; j < 4; ++j) {
        int row  = wn * 64 + j * 16 + cc;
        int slot = (ks * 4 + (lane >> 4)) ^ (row & 7);
        bfr[j] = *(const short8*)(sB[cur] + row * 64 + slot * 8);
      }
#pragma unroll
      for (int i = 0; i < 4; ++i)
#pragma unroll
        for (int j = 0; j < 4; ++j)
          acc[i][j] = __builtin_amdgcn_mfma_f32_16x16x32_bf16(af[i], bfr[j], acc[i][j], 0, 0, 0);
    }
    __syncthreads();
  }

  // C write, head-sliced hs[hh][node][128]. C/D layout: col=lane&15, row=(lane>>4)*4+reg
  const int r4 = (lane >> 4) * 4;
#pragma unroll
  for (int i = 0; i < 4; ++i)
#pragma unroll
    for (int j = 0; j < 4; ++j) {
      int cin = wn * 64 + j * 16 + cc;
#pragma unroll
      for (int rg = 0; rg < 4; ++rg) {
        int gr = bm0 + wm * 64 + i * 16 + r4 + rg;
        Cs[((size_t)hh * N + gr) * 128 + cin] = f2bf(acc[i][j][rg]);
      }
    }
  // el/er partials -> LDS (2 partials per row), combine, store
  float alv[4], arv[4];
#pragma unroll
  for (int j = 0; j < 4; ++j) {
    int cl = wn * 64 + j * 16 + cc;
    alv[j] = attn_l[hh * 128 + cl];
    arv[j] = attn_r[hh * 128 + cl];
  }
#pragma unroll
  for (int i = 0; i < 4; ++i)
#pragma unroll
    for (int rg = 0; rg < 4; ++rg) {
      float pl = 0.f, pr = 0.f;
#pragma unroll
      for (int j = 0; j < 4; ++j) {
        float v = acc[i][j][rg];
        pl += v * alv[j]; pr += v * arv[j];
      }
#pragma unroll
      for (int d = 1; d < 16; d <<= 1) {
        pl += __shfl_xor(pl, d);
        pr += __shfl_xor(pr, d);
      }
      if (cc == 0) {
        int row = wm * 64 + i * 16 + r4 + rg;
        sEl[row][wn] = pl;
        sEr[row][wn] = pr;
      }
    }
  __syncthreads();
  if (tid < 128) {
    int gr = bm0 + tid;
    el[gr * 4 + hh] = sEl[tid][0] + sEl[tid][1];
    er[gr * 4 + hh] = sEr[tid][0] + sEr[tid][1];
  }
}

// ---------- K3: 4-slice aggregation, 2 NODES PER WAVE (interleaved independent chains) ----------
// Wave owns nodes nd0 and nd0+4 of one slice. Both prologues issue in parallel; the gather loop
// walks max(n0,n1) with wave-uniform guards (if base<n_i -> SALU only, no divergence). The two
// chains are independent -> compiler interleaves, one node's VALU hides the other's loads.
// Wave count halves (fixed costs amortized over 2 nodes). ssum folded into loop as before.
__global__ __launch_bounds__(256) void k_aggregate(const int* __restrict__ cnt, const int* __restrict__ bucket,
                                                   const float* __restrict__ el, const float* __restrict__ er,
                                                   const short* __restrict__ hs, const float* __restrict__ bias,
                                                   float* __restrict__ out, int N) {
  const int b    = blockIdx.x;
  const int s    = (b >> 1) & 3;                       // head/slice
  const int nt   = (b >> 3) * 2 + (b & 1);             // node-tile of 8
  const int nd0  = nt * 8 + (threadIdx.x >> 6);
  const int nd1  = nd0 + 4;
  const int lane = threadIdx.x & 63;
  const int g    = lane >> 4;                          // edge-parallel group 0..3
  const int cl   = lane & 15;                          // 16B chunk within 128-col slice

  // parallel prologue for both nodes (6 independent loads)
  int n0_raw = cnt[nd0];
  int n1_raw = cnt[nd1];
  int i0_raw = bucket[(size_t)nd0 * CAP + lane];
  int i1_raw = bucket[(size_t)nd1 * CAP + lane];
  float ern0 = er[nd0 * 4 + s];
  float ern1 = er[nd1 * 4 + s];

  int n0 = (n0_raw < CAP) ? n0_raw : CAP;
  int n1 = (n1_raw < CAP) ? n1_raw : CAP;
  int idx0 = (lane < n0) ? i0_raw : 0;
  int idx1 = (lane < n1) ? i1_raw : 0;
  float x0 = el[idx0 * 4 + s] + ern0;
  float x1 = el[idx1 * 4 + s] + ern1;
  x0 = (x0 > 0.f) ? x0 : 0.2f * x0;
  x1 = (x1 > 0.f) ? x1 : 0.2f * x1;
  float wgt0 = (lane < n0) ? __expf(x0) : 0.f;
  float wgt1 = (lane < n1) ? __expf(x1) : 0.f;

  const short* hbase = hs + (size_t)s * N * 128;
  float acc0[8], acc1[8];
#pragma unroll
  for (int j = 0; j < 8; ++j) { acc0[j] = 0.f; acc1[j] = 0.f; }
  float sw0 = 0.f, sw1 = 0.f;

  const int maxn = (n0 > n1) ? n0 : n1;
  for (int base = 0; base < maxn; base += 8) {         // 2-deep per node, uniform guards
    if (base < n0) {
      int e0 = base + g, e1 = base + 4 + g;
      int s0 = __shfl(idx0, e0), s1 = __shfl(idx0, e1);
      float w0 = __shfl(wgt0, e0), w1 = __shfl(wgt0, e1);
      uint4 v0 = ((const uint4*)(hbase + (size_t)s0 * 128))[cl];
      uint4 v1 = ((const uint4*)(hbase + (size_t)s1 * 128))[cl];
      sw0 += w0 + w1;
      acc0[0] += w0 * bf_lo(v0.x) + w1 * bf_lo(v1.x);
      acc0[1] += w0 * bf_hi(v0.x) + w1 * bf_hi(v1.x);
      acc0[2] += w0 * bf_lo(v0.y) + w1 * bf_lo(v1.y);
      acc0[3] += w0 * bf_hi(v0.y) + w1 * bf_hi(v1.y);
      acc0[4] += w0 * bf_lo(v0.z) + w1 * bf_lo(v1.z);
      acc0[5] += w0 * bf_hi(v0.z) + w1 * bf_hi(v1.z);
      acc0[6] += w0 * bf_lo(v0.w) + w1 * bf_lo(v1.w);
      acc0[7] += w0 * bf_hi(v0.w) + w1 * bf_hi(v1.w);
    }
    if (base < n1) {
      int e0 = base + g, e1 = base + 4 + g;
      int s0 = __shfl(idx1, e0), s1 = __shfl(idx1, e1);
      float w0 = __shfl(wgt1, e0), w1 = __shfl(wgt1, e1);
      uint4 v0 = ((const uint4*)(hbase + (size_t)s0 * 128))[cl];
      uint4 v1 = ((const uint4*)(hbase + (size_t)s1 * 128))[cl];
      sw1 += w0 + w1;
      acc1[0] += w0 * bf_lo(v0.x) + w1 * bf_lo(v1.x);
      acc1[1] += w0 * bf_hi(v0.x) + w1 * bf_hi(v1.x);
      acc1[2] += w0 * bf_lo(v0.y) + w1 * bf_lo(v1.y);
      acc1[3] += w0 * bf_hi(v0.y) + w1 * bf_hi(v1.y);
      acc1[4] += w0 * bf_lo(v0.z) + w1 * bf_lo(v1.z);
      acc1[5] += w0 * bf_hi(v0.z) + w1 * bf_hi(v1.z);
      acc1[6] += w0 * bf_lo(v0.w) + w1 * bf_lo(v1.w);
      acc1[7] += w0 * bf_hi(v0.w) + w1 * bf_hi(v1.w);
    }
  }

  // combine the 4 edge-groups for both nodes (groups live in lane bits 4-5)
#pragma unroll
  for (int d = 16; d < 64; d <<= 1) {
    sw0 += __shfl_xor(sw0, d);
    sw1 += __shfl_xor(sw1, d);
#pragma unroll
    for (int j = 0; j < 8; ++j) {
      acc0[j] += __shfl_xor(acc0[j], d);
      acc1[j] += __shfl_xor(acc1[j], d);
    }
  }

  if (g == 0) {
    int c0 = s * 128 + cl * 8;
    float4 b0 = *(const float4*)(bias + c0);
    float4 b1 = *(const float4*)(bias + c0 + 4);
    {
      float inv = 1.f / sw0;
      float4 o0, o1;
      o0.x = acc0[0] * inv + b0.x; o0.y = acc0[1] * inv + b0.y;
      o0.z = acc0[2] * inv + b0.z; o0.w = acc0[3] * inv + b0.w;
      o1.x = acc0[4] * inv + b1.x; o1.y = acc0[5] * inv + b1.y;
      o1.z = acc0[6] * inv + b1.z; o1.w = acc0[7] * inv + b1.w;
      float* op = out + (size_t)nd0 * 512 + c0;
      *(float4*)op = o0;
      *(float4*)(op + 4) = o1;
    }
    {
      float inv = 1.f / sw1;
      float4 o0, o1;
      o0.x = acc1[0] * inv + b0.x; o0.y = acc1[1] * inv + b0.y;
      o0.z = acc1[2] * inv + b0.z; o0.w = acc1[3] * inv + b0.w;
      o1.x = acc1[4] * inv + b1.x; o1.y = acc1[5] * inv + b1.y;
      o1.z = acc1[6] * inv + b1.z; o1.w = acc1[7] * inv + b1.w;
      float* op = out + (size_t)nd1 * 512 + c0;
      *(float4*)op = o0;
      *(float4*)(op + 4) = o1;
    }
  }
}

// ---------- launch ----------
extern "C" void kernel_launch(void* const* d_in, const int* in_sizes, int n_in,
                              void* d_out, int out_size, void* d_ws, size_t ws_size,
                              hipStream_t stream) {
  const float* text   = (const float*)d_in[0];
  const float* weight = (const float*)d_in[1];
  const float* fcw    = (const float*)d_in[2];
  const float* attn_l = (const float*)d_in[3];
  const float* attn_r = (const float*)d_in[4];
  const float* bias   = (const float*)d_in[5];
  const int*   src    = (const int*)d_in[6];
  const int*   dst    = (const int*)d_in[7];
  const int E = in_sizes[6];
  const int N = in_sizes[0] / 512;   // 16384

  char* ws = (char*)d_ws;
  size_t o = 0;
  auto carve = [&](size_t bytes) { void* p = ws + o; o = (o + bytes + 255) & ~(size_t)255; return p; };
  short* w2t    = (short*)carve((size_t)512 * 512 * 2);
  short* textb  = (short*)carve((size_t)N * 512 * 2);   // bf16 text
  short* hs     = (short*)carve((size_t)N * 512 * 2);   // head-sliced [4][N][128]
  float* el     = (float*)carve((size_t)N * 4 * 4);
  float* er     = (float*)carve((size_t)N * 4 * 4);
  int*   cnt    = (int*)carve((size_t)N * 4);
  int*   bucket = (int*)carve((size_t)N * CAP * 4);

  k_w2t_cvt<<<NW2T + NCVT, 256, 0, stream>>>(weight, fcw, text, w2t, textb, cnt);
  k_gemm_scatter<<<NGEMM + NSCAT, 256, 0, stream>>>(textb, w2t, hs, el, er, attn_l, attn_r,
                                                    src, dst, cnt, bucket, E, N);
  k_aggregate<<<N * 4 / 8, 256, 0, stream>>>(cnt, bucket, el, er, hs, bias, (float*)d_out, N);
}